// Round 13
// baseline (174.940 us; speedup 1.0000x reference)
//
#include <hip/hip_runtime.h>
#include <hip/hip_bf16.h>

#define BS 4
#define L 2048
#define H 12
#define HD 64
#define R 16
#define HID 768
#define MARGIN 0.02f
#define FIXCAP 16384
#define FIXGRID 1024
// M = BS*L = 8192, N = 768, K = 768

typedef __attribute__((ext_vector_type(8))) short s8v;   // 8 bf16 (4 VGPRs)
typedef __attribute__((ext_vector_type(4))) float f32x4;

static __device__ __forceinline__ unsigned short f2bf_bits(float f) {
    __hip_bfloat16 h = __float2bfloat16(f);
    return *reinterpret_cast<unsigned short*>(&h);
}

// ---------------------------------------------------------------------------
// Prep: both W (k,n) fp32 -> Wt (n,k) bf16 transposes; block 0 zeroes fixcnt.
// ---------------------------------------------------------------------------
__global__ __launch_bounds__(256) void prep_kernel(
    const float* __restrict__ K1w, const float* __restrict__ V1w,
    __hip_bfloat16* __restrict__ WtK, __hip_bfloat16* __restrict__ WtV,
    int* __restrict__ fixcnt)
{
    if (blockIdx.x == 0 && threadIdx.x == 0) *fixcnt = 0;
    const int t = blockIdx.x;
    const int z = t / 576, rem = t % 576;
    const float* in = z ? V1w : K1w;
    __hip_bfloat16* out = z ? WtV : WtK;
    __shared__ float s[32][33];
    const int c = threadIdx.x & 31, r8 = threadIdx.x >> 5;
    const int kt = (rem / 24) * 32, nt = (rem % 24) * 32;
#pragma unroll
    for (int rr = 0; rr < 4; ++rr) {
        int k = r8 + rr * 8;
        s[k][c] = in[(size_t)(kt + k) * HID + nt + c];
    }
    __syncthreads();
#pragma unroll
    for (int rr = 0; rr < 4; ++rr) {
        int n = r8 + rr * 8;
        out[(size_t)(nt + n) * HID + kt + c] = __float2bfloat16(s[c][n]);
    }
}

// ---------------------------------------------------------------------------
// Dual-GEMM v5b: 512-thread blocks, 64M x 128N tile computing the V1 tile AND
// the K-dots tile for the same (m0,n0) — A staged + converted ONCE for both.
// Grid (128,6) = 768 blocks x 8 waves = 24 waves/CU.
// B staging: each thread covers TWO rows (br and br+64) — R12 bug was only
// staging rows 0..63 of the 128-row B tiles.
// XOR chunk swizzle p = c ^ ((r>>1)&3) (0 conflicts, validated R8; holds for
// br+64 since ((br+64)>>1)&3 == (br>>1)&3).
// ---------------------------------------------------------------------------
__global__ __launch_bounds__(512) void gemm_fused(
    const float* __restrict__ A,             // (8192, 768) fp32 hs
    const __hip_bfloat16* __restrict__ WtK,  // (768, 768) = K1_w^T bf16
    const __hip_bfloat16* __restrict__ WtV,  // (768, 768) = V1_w^T bf16
    const float* __restrict__ K1b,
    const float* __restrict__ V1b,
    const float* __restrict__ RH,            // (H*HD) flat
    float* __restrict__ dots,                // (BS*H, L) fp32
    int* __restrict__ fixlist,               // packed row*16+head
    int* __restrict__ fixcnt,
    __hip_bfloat16* __restrict__ C)          // (8192, 768) relu'd V1
{
    __shared__ alignas(16) __hip_bfloat16 As[64 * 32];
    __shared__ alignas(16) __hip_bfloat16 BsV[128 * 32];
    __shared__ alignas(16) __hip_bfloat16 BsK[128 * 32];

    const int tid = threadIdx.x;              // 0..511
    const int m0 = blockIdx.x * 64;
    const int n0 = blockIdx.y * 128;

    // B staging: tid>>8 selects matrix (0=V,1=K); rows br and br+64.
    const int bmx = tid >> 8;
    const int br = (tid & 255) >> 2, bc = tid & 3;
    const int bp = bc ^ ((br >> 1) & 3);
    const __hip_bfloat16* gB =
        (bmx ? WtK : WtV) + (size_t)(n0 + br) * HID + bc * 8;
    __hip_bfloat16* BsD = bmx ? BsK : BsV;
    uint4* wB0 = (uint4*)(BsD + br * 32 + bp * 8);
    uint4* wB1 = (uint4*)(BsD + (br + 64) * 32 + bp * 8);

    // A staging (threads 0..255 only)
    const int ar = tid >> 2, ac = tid & 3;
    const int ap = ac ^ ((ar >> 1) & 3);
    const float* gA = A + (size_t)(m0 + (ar & 63)) * HID + ac * 8;
    uint4* wA = (uint4*)(As + (ar & 63) * 32 + ap * 8);

    // compute mapping
    const int w = tid >> 6, lane = tid & 63;
    const bool isV = w < 4;
    const int wl = w & 3, wm2 = wl & 1, wn2 = wl >> 1;
    const int quad = lane >> 4, lm = lane & 15;
    const int fsw = (lm >> 1) & 3;
    const __hip_bfloat16* pA = &As[(wm2 * 32 + lm) * 32 + ((quad ^ fsw) * 8)];
    const __hip_bfloat16* pB =
        (isV ? BsV : BsK) + (wn2 * 64 + lm) * 32 + ((quad ^ fsw) * 8);

    f32x4 acc[2][4] = {};

    // prologue: load tile 0
    float4 a0, a1;
    uint4 bv0 = *(const uint4*)gB;
    uint4 bv1 = *(const uint4*)(gB + (size_t)64 * HID);
    if (tid < 256) { a0 = *(const float4*)gA; a1 = *(const float4*)(gA + 4); }
    gA += 32; gB += 32;

    for (int it = 0; it < HID / 32; ++it) {
        if (tid < 256) {
            union { unsigned short s[8]; uint4 v; } u;
            u.s[0] = f2bf_bits(a0.x); u.s[1] = f2bf_bits(a0.y);
            u.s[2] = f2bf_bits(a0.z); u.s[3] = f2bf_bits(a0.w);
            u.s[4] = f2bf_bits(a1.x); u.s[5] = f2bf_bits(a1.y);
            u.s[6] = f2bf_bits(a1.z); u.s[7] = f2bf_bits(a1.w);
            *wA = u.v;
        }
        *wB0 = bv0;
        *wB1 = bv1;
        __syncthreads();

        if (it + 1 < HID / 32) {
            bv0 = *(const uint4*)gB;
            bv1 = *(const uint4*)(gB + (size_t)64 * HID);
            if (tid < 256) { a0 = *(const float4*)gA; a1 = *(const float4*)(gA + 4); }
            gA += 32; gB += 32;
        }

        s8v af[2], bf[4];
#pragma unroll
        for (int i = 0; i < 2; ++i) af[i] = *(const s8v*)(pA + i * 16 * 32);
#pragma unroll
        for (int j = 0; j < 4; ++j) bf[j] = *(const s8v*)(pB + j * 16 * 32);
#pragma unroll
        for (int i = 0; i < 2; ++i)
#pragma unroll
            for (int j = 0; j < 4; ++j)
                acc[i][j] = __builtin_amdgcn_mfma_f32_16x16x32_bf16(
                    af[i], bf[j], acc[i][j], 0, 0, 0);
        __syncthreads();
    }

    if (isV) {
        // C/D layout: col = lane&15, row = quad*4 + reg  [m89/m91 verified]
#pragma unroll
        for (int i = 0; i < 2; ++i) {
            int row_b = m0 + wm2 * 32 + i * 16 + quad * 4;
#pragma unroll
            for (int j = 0; j < 4; ++j) {
                int col = n0 + wn2 * 64 + j * 16 + lm;
                float bsv = V1b[col];
#pragma unroll
                for (int reg = 0; reg < 4; ++reg) {
                    float v = acc[i][j][reg] + bsv;
                    C[(size_t)(row_b + reg) * HID + col] =
                        __float2bfloat16(fmaxf(v, 0.f));
                }
            }
        }
    } else {
        const int head = 2 * blockIdx.y + wn2;  // wave covers one head's cols
        float bj[4], rj[4];
#pragma unroll
        for (int j = 0; j < 4; ++j) {
            bj[j] = K1b[head * 64 + j * 16 + lm];
            rj[j] = RH[head * 64 + j * 16 + lm];
        }
#pragma unroll
        for (int i = 0; i < 2; ++i) {
            int row0 = m0 + wm2 * 32 + i * 16 + quad * 4;
#pragma unroll
            for (int reg = 0; reg < 4; ++reg) {
                float p = 0.f;
#pragma unroll
                for (int j = 0; j < 4; ++j)
                    p = fmaf(fmaxf(acc[i][j][reg] + bj[j], 0.f), rj[j], p);
                p += __shfl_xor(p, 1, 64);
                p += __shfl_xor(p, 2, 64);
                p += __shfl_xor(p, 4, 64);
                p += __shfl_xor(p, 8, 64);
                if (lm == 0) {
                    int row = row0 + reg;
                    int b = row >> 11, l = row & (L - 1);
                    dots[((b * H + head) << 11) + l] = p;
                    if (fabsf(p - 0.5f) < MARGIN) {
                        int idx = atomicAdd(fixcnt, 1);
                        if (idx < FIXCAP) fixlist[idx] = row * 16 + head;
                    }
                }
            }
        }
    }
}

// ---------------------------------------------------------------------------
// Fix-up: one block per flagged row (grid-stride over compacted list).
// ---------------------------------------------------------------------------
__global__ __launch_bounds__(256) void fixup_kernel(
    const float* __restrict__ hs,      // (BS*L, 768) fp32
    const float* __restrict__ W,       // (768, 768) K1_w fp32
    const float* __restrict__ bias,
    const float* __restrict__ RH,
    const int* __restrict__ fixlist,
    const int* __restrict__ fixcnt,
    float* __restrict__ dots)
{
    __shared__ float hrow[HID];
    __shared__ float psum[4][64];

    const int tid = threadIdx.x;
    const int n = min(*fixcnt, FIXCAP);

    for (int item = blockIdx.x; item < n; item += FIXGRID) {
        int packed = fixlist[item];
        int row = packed >> 4, head = packed & 15;
        int b = row >> 11, l = row & (L - 1);

#pragma unroll
        for (int i = 0; i < 3; ++i)
            hrow[tid + i * 256] = hs[(size_t)row * HID + tid + i * 256];
        __syncthreads();

        const int d = tid & 63, kq = tid >> 6;
        float a0 = 0.f, a1 = 0.f;
#pragma unroll 8
        for (int i = 0; i < 96; ++i) {
            int k = kq + i * 8;
            a0 = fmaf(W[(size_t)k * HID + head * 64 + d], hrow[k], a0);
            a1 = fmaf(W[(size_t)(k + 4) * HID + head * 64 + d], hrow[k + 4], a1);
        }
        psum[kq][d] = a0 + a1;
        __syncthreads();
        if (tid < 64) {
            float v = psum[0][tid] + psum[1][tid] + psum[2][tid] +
                      psum[3][tid] + bias[head * 64 + tid];
            v = fmaxf(v, 0.f) * RH[head * 64 + tid];
#pragma unroll
            for (int s = 1; s < 64; s <<= 1) v += __shfl_xor(v, s, 64);
            if (tid == 0) dots[((size_t)(b * H + head) << 11) + l] = v;
        }
        __syncthreads();
    }
}

// ---------------------------------------------------------------------------
// Scan: rank/select tables. Pg[bh][l] = # valid in [1..l]; Sg[bh][j] = j-th
// valid index (1-based).
// ---------------------------------------------------------------------------
__global__ __launch_bounds__(256) void scan_kernel(
    const float* __restrict__ dots,   // (BS*H, L)
    unsigned short* __restrict__ Pg,  // (BS*H, L)
    unsigned short* __restrict__ Sg)  // (BS*H, L)
{
    __shared__ int wsum[4];
    const int bh = blockIdx.x;
    const int tid = threadIdx.x;
    const int base = tid * 8;
    const int lane = tid & 63, w = tid >> 6;

    int m[8], c[8];
    int run = 0;
#pragma unroll
    for (int i = 0; i < 8; ++i) {
        int l = base + i;
        m[i] = (l >= 1 && dots[((size_t)bh << 11) + l] > 0.5f) ? 1 : 0;
        run += m[i];
        c[i] = run;
    }
    int sc = run;
#pragma unroll
    for (int s = 1; s < 64; s <<= 1) {
        int v = __shfl_up(sc, s, 64);
        if (lane >= s) sc += v;
    }
    if (lane == 63) wsum[w] = sc;
    __syncthreads();
    int woff = 0;
    for (int i = 0; i < 4; ++i) if (i < w) woff += wsum[i];
    const int ex = woff + sc - run;

    union { unsigned short s[8]; uint4 q; } up;
#pragma unroll
    for (int i = 0; i < 8; ++i) {
        int pc = ex + c[i];
        up.s[i] = (unsigned short)pc;
        if (m[i]) Sg[((size_t)bh << 11) + pc] = (unsigned short)(base + i);
    }
    *(uint4*)&Pg[((size_t)bh << 11) + base] = up.q;
}

// ---------------------------------------------------------------------------
// Gather v5 (unchanged): block = (ltile of 64, bh); stage S-range rows to
// LDS, precomputed slot table, coalesced float4 stores.
// ---------------------------------------------------------------------------
__global__ __launch_bounds__(256) void gather_kernel(
    const __hip_bfloat16* __restrict__ V1,   // (8192, 768) bf16
    const unsigned short* __restrict__ Pg,
    const unsigned short* __restrict__ Sg,
    const float* __restrict__ bw,            // (H, 2R)
    float* __restrict__ out)                 // (8192, 768) fp32
{
    __shared__ __hip_bfloat16 Vs[97 * 72];   // slot pitch 144 B (16B aligned)
    __shared__ unsigned short Ptile[65];     // P[l0-1 .. l0+63]
    __shared__ short slots[64 * 32];         // [ll][r] -> staging slot (0=zero)
    __shared__ float sw[2 * R];
    __shared__ int sT;

    const int bh = blockIdx.y;
    const int b = bh / H, h = bh % H;
    const int l0 = blockIdx.x * 64;
    const int tid = threadIdx.x;

    if (tid < 65) {
        int l = l0 - 1 + tid;
        Ptile[tid] = (l >= 0) ? Pg[((size_t)bh << 11) + l] : (unsigned short)0;
    } else if (tid < 65 + 2 * R) {
        sw[tid - 65] = bw[h * (2 * R) + (tid - 65)];
    } else if (tid == 100) {
        sT = Pg[((size_t)bh << 11) + (L - 1)];
    }
    __syncthreads();

    const int T = sT;
    const int a = max(1, (int)Ptile[1] - (R - 1));
    const int bj = min(T, (int)Ptile[63] + R);
    const int nr = max(0, bj - a + 1);       // <= 95

    const __hip_bfloat16* Vbase = V1 + (size_t)b * L * HID + h * HD;
    for (int it = tid; it < (nr + 1) * 8; it += 256) {
        int slot = it >> 3, oct = it & 7;
        int row = slot ? (int)Sg[((size_t)bh << 11) + a + slot - 1] : 0;
        *(uint4*)&Vs[slot * 72 + oct * 8] =
            *(const uint4*)&Vbase[(size_t)row * HID + oct * 8];
    }
#pragma unroll
    for (int q = 0; q < 8; ++q) {
        int i = tid + q * 256;
        int ll = i >> 5, r = i & 31;
        int l = l0 + ll;
        int Pl = Ptile[1 + ll], Plm1 = Ptile[ll];
        int j, ok;
        if (r < R) { j = Pl - r;             ok = (l >= 1) && (j >= 1); }
        else       { j = Plm1 + 1 + (r - R); ok = (l >= 1) && (j <= T); }
        slots[i] = (short)(ok ? (j - a + 1) : 0);
    }
    __syncthreads();

    const int d8 = tid & 7, lg = tid >> 3;   // lg 0..31

#pragma unroll
    for (int li = 0; li < 2; ++li) {
        int ll = lg + 32 * li;               // 0..63
        int l = l0 + ll;
        float acc0 = 0.f, acc1 = 0.f, acc2 = 0.f, acc3 = 0.f;
        float acc4 = 0.f, acc5 = 0.f, acc6 = 0.f, acc7 = 0.f;
#pragma unroll
        for (int r = 0; r < 2 * R; ++r) {
            int slot = slots[ll * 32 + r];   // broadcast within d8 octet
            float wv = sw[r];
            uint4 uv = *(const uint4*)&Vs[slot * 72 + d8 * 8];
            acc0 = fmaf(wv, __uint_as_float(uv.x << 16), acc0);
            acc1 = fmaf(wv, __uint_as_float(uv.x & 0xffff0000u), acc1);
            acc2 = fmaf(wv, __uint_as_float(uv.y << 16), acc2);
            acc3 = fmaf(wv, __uint_as_float(uv.y & 0xffff0000u), acc3);
            acc4 = fmaf(wv, __uint_as_float(uv.z << 16), acc4);
            acc5 = fmaf(wv, __uint_as_float(uv.z & 0xffff0000u), acc5);
            acc6 = fmaf(wv, __uint_as_float(uv.w << 16), acc6);
            acc7 = fmaf(wv, __uint_as_float(uv.w & 0xffff0000u), acc7);
        }
        float* op = &out[((size_t)b * L + l) * HID + h * HD + d8 * 8];
        float4 o0, o1;
        o0.x = acc0; o0.y = acc1; o0.z = acc2; o0.w = acc3;
        o1.x = acc4; o1.y = acc5; o1.z = acc6; o1.w = acc7;
        *(float4*)op = o0;
        *(float4*)(op + 4) = o1;
    }
}

extern "C" void kernel_launch(void* const* d_in, const int* in_sizes, int n_in,
                              void* d_out, int out_size, void* d_ws, size_t ws_size,
                              hipStream_t stream) {
    const float* hs  = (const float*)d_in[0];
    const float* K1w = (const float*)d_in[1];
    const float* K1b = (const float*)d_in[2];
    const float* V1w = (const float*)d_in[3];
    const float* V1b = (const float*)d_in[4];
    const float* RH  = (const float*)d_in[5];
    const float* bw  = (const float*)d_in[6];
    float* out = (float*)d_out;

    // workspace layout (total ~15.8 MB)
    char* ws = (char*)d_ws;
    __hip_bfloat16* WtV = (__hip_bfloat16*)ws;                 // 1,179,648
    __hip_bfloat16* WtK = (__hip_bfloat16*)(ws + 1179648);     // 1,179,648
    __hip_bfloat16* V1  = (__hip_bfloat16*)(ws + 2359296);     // 12,582,912
    float* dots = (float*)(ws + 14942208);                     //   393,216
    unsigned short* Pg = (unsigned short*)(ws + 15335424);     //   196,608
    unsigned short* Sg = (unsigned short*)(ws + 15532032);     //   196,608
    int* fixlist = (int*)(ws + 15728640);                      //    65,536
    int* fixcnt  = (int*)(ws + 15794176);                      //         4

    prep_kernel<<<2 * 24 * 24, 256, 0, stream>>>(K1w, V1w, WtK, WtV, fixcnt);
    gemm_fused<<<dim3(BS * L / 64, 6), 512, 0, stream>>>(
        hs, WtK, WtV, K1b, V1b, RH, dots, fixlist, fixcnt, V1);
    fixup_kernel<<<FIXGRID, 256, 0, stream>>>(hs, K1w, K1b, RH, fixlist, fixcnt, dots);
    scan_kernel<<<BS * H, 256, 0, stream>>>(dots, Pg, Sg);
    gather_kernel<<<dim3(L / 64, BS * H), 256, 0, stream>>>(V1, Pg, Sg, bw, out);
}

// Round 14
// 170.423 us; speedup vs baseline: 1.0265x; 1.0265x over previous
//
#include <hip/hip_runtime.h>
#include <hip/hip_bf16.h>

#define BS 4
#define L 2048
#define H 12
#define HD 64
#define R 16
#define HID 768
#define MARGIN 0.02f
#define FIXCAP 16384
#define FIXGRID 1024
// M = BS*L = 8192, N = 768, K = 768

typedef __attribute__((ext_vector_type(8))) short s8v;   // 8 bf16 (4 VGPRs)
typedef __attribute__((ext_vector_type(4))) float f32x4;

typedef __attribute__((address_space(1))) const void as1_void;
typedef __attribute__((address_space(3))) void as3_void;
// async global->LDS DMA, 16B/lane; LDS dest = wave-uniform base + lane*16
#define GLOAD_LDS16(g, l) \
    __builtin_amdgcn_global_load_lds((as1_void*)(g), (as3_void*)(l), 16, 0, 0)

static __device__ __forceinline__ unsigned short f2bf_bits(float f) {
    __hip_bfloat16 h = __float2bfloat16(f);
    return *reinterpret_cast<unsigned short*>(&h);
}

// ---------------------------------------------------------------------------
// Prep merged: blocks 0..1151 transpose K1_w/V1_w (k,n)fp32 -> (n,k)bf16;
// blocks 1152.. convert hs fp32 -> bf16 (float4/ushort4). Block 0 zeroes
// fixcnt. One launch replaces R8's convert_hs + transpose_wt2.
// ---------------------------------------------------------------------------
__global__ __launch_bounds__(256) void prep_kernel(
    const float* __restrict__ K1w, const float* __restrict__ V1w,
    const float* __restrict__ hs,
    __hip_bfloat16* __restrict__ WtK, __hip_bfloat16* __restrict__ WtV,
    __hip_bfloat16* __restrict__ Abf,
    int* __restrict__ fixcnt)
{
    const int blk = blockIdx.x;
    if (blk == 0 && threadIdx.x == 0) *fixcnt = 0;

    if (blk < 1152) {                       // transpose job
        const int z = blk / 576, rem = blk % 576;
        const float* in = z ? V1w : K1w;
        __hip_bfloat16* out = z ? WtV : WtK;
        __shared__ float s[32][33];
        const int c = threadIdx.x & 31, r8 = threadIdx.x >> 5;
        const int kt = (rem / 24) * 32, nt = (rem % 24) * 32;
#pragma unroll
        for (int rr = 0; rr < 4; ++rr) {
            int k = r8 + rr * 8;
            s[k][c] = in[(size_t)(kt + k) * HID + nt + c];
        }
        __syncthreads();
#pragma unroll
        for (int rr = 0; rr < 4; ++rr) {
            int n = r8 + rr * 8;
            out[(size_t)(nt + n) * HID + kt + c] = __float2bfloat16(s[c][n]);
        }
    } else {                                // convert job
        int i = ((blk - 1152) * 256 + threadIdx.x) * 4;
        float4 v = *(const float4*)&hs[i];
        ushort4 o;
        o.x = f2bf_bits(v.x); o.y = f2bf_bits(v.y);
        o.z = f2bf_bits(v.z); o.w = f2bf_bits(v.w);
        *(ushort4*)&Abf[i] = o;
    }
}

// ---------------------------------------------------------------------------
// Fused dual GEMM (R8 config — best measured: 44.4 us, 0 conflicts).
// bf16 MFMA 16x16x32, 128x128 tile, BK=32, global_load_lds width=16 into
// unpadded [128][32] LDS with XOR chunk swizzle (chunk c of row r at c^((r>>1)&3)):
//   - DMA writes lane-sequential = conflict-free
//   - frag ds_read_b128: banks 16(lm&1)+4(quad^((lm>>1)&3)) -> 2-way = free
// blockIdx.y < 6  -> V1 tile:  +bias, relu, store bf16.
// blockIdx.y >= 6 -> K-dots:   +bias, relu, *RH, 16-lane reduce -> dots,
//                    near-threshold rows -> fixlist.
// ---------------------------------------------------------------------------
__global__ __launch_bounds__(256) void gemm_fused(
    const __hip_bfloat16* __restrict__ A,    // (8192, 768) bf16
    const __hip_bfloat16* __restrict__ WtK,  // (768, 768) = K1_w^T bf16
    const __hip_bfloat16* __restrict__ WtV,  // (768, 768) = V1_w^T bf16
    const float* __restrict__ K1b,
    const float* __restrict__ V1b,
    const float* __restrict__ RH,            // (H*HD) flat
    float* __restrict__ dots,                // (BS*H, L) fp32
    int* __restrict__ fixlist,               // packed row*16+head
    int* __restrict__ fixcnt,
    __hip_bfloat16* __restrict__ C)          // (8192, 768) relu'd V1
{
    __shared__ alignas(16) __hip_bfloat16 As[128 * 32];
    __shared__ alignas(16) __hip_bfloat16 Bs[128 * 32];

    const int tid = threadIdx.x;
    const bool isV = blockIdx.y < 6;
    const int m0 = blockIdx.x * 128;
    const int n0 = (isV ? blockIdx.y : blockIdx.y - 6) * 128;
    const __hip_bfloat16* Bt = isV ? WtV : WtK;

    const int wid = tid >> 6, lane = tid & 63;
    const int quad = lane >> 4, lm = lane & 15;
    const int wm = wid & 1, wn = wid >> 1;

    // staging pointers: lane covers row rsub = lane>>2 of a 16-row chunk,
    // fetching swizzled global chunk csw (16 B) of that row's 64-B k-window.
    const int rsub = lane >> 2;
    const int csw  = (lane & 3) ^ ((lane >> 3) & 3);
    const __hip_bfloat16* gA0 =
        A + (size_t)(m0 + 32 * wid + rsub) * HID + csw * 8;
    const __hip_bfloat16* gA1 = gA0 + (size_t)16 * HID;
    const __hip_bfloat16* gB0 =
        Bt + (size_t)(n0 + 32 * wid + rsub) * HID + csw * 8;
    const __hip_bfloat16* gB1 = gB0 + (size_t)16 * HID;
    __hip_bfloat16* lA0 = &As[(32 * wid) * 32];
    __hip_bfloat16* lA1 = &As[(32 * wid + 16) * 32];
    __hip_bfloat16* lB0 = &Bs[(32 * wid) * 32];
    __hip_bfloat16* lB1 = &Bs[(32 * wid + 16) * 32];

    // frag-read swizzled base (lane-constant)
    const int fsw = (lm >> 1) & 3;
    const __hip_bfloat16* pA = &As[(wm * 64 + lm) * 32 + ((quad ^ fsw) * 8)];
    const __hip_bfloat16* pB = &Bs[(wn * 64 + lm) * 32 + ((quad ^ fsw) * 8)];

    f32x4 acc[4][4] = {};

    for (int k0 = 0; k0 < HID; k0 += 32) {
        GLOAD_LDS16(gA0, lA0);
        GLOAD_LDS16(gA1, lA1);
        GLOAD_LDS16(gB0, lB0);
        GLOAD_LDS16(gB1, lB1);
        gA0 += 32; gA1 += 32; gB0 += 32; gB1 += 32;
        __syncthreads();          // drains vmcnt (DMA complete)

        s8v af[4], bf[4];
#pragma unroll
        for (int i = 0; i < 4; ++i)
            af[i] = *(const s8v*)(pA + i * 16 * 32);
#pragma unroll
        for (int j = 0; j < 4; ++j)
            bf[j] = *(const s8v*)(pB + j * 16 * 32);
#pragma unroll
        for (int i = 0; i < 4; ++i)
#pragma unroll
            for (int j = 0; j < 4; ++j)
                acc[i][j] = __builtin_amdgcn_mfma_f32_16x16x32_bf16(
                    af[i], bf[j], acc[i][j], 0, 0, 0);
        __syncthreads();          // protect LDS from next iter's DMA
    }

    if (isV) {
        // C/D layout: col = lane&15, row = quad*4 + reg  [m89/m91 verified]
#pragma unroll
        for (int i = 0; i < 4; ++i) {
            int row_b = m0 + wm * 64 + i * 16 + quad * 4;
#pragma unroll
            for (int j = 0; j < 4; ++j) {
                int col = n0 + wn * 64 + j * 16 + lm;
                float bsv = V1b[col];
#pragma unroll
                for (int reg = 0; reg < 4; ++reg) {
                    float v = acc[i][j][reg] + bsv;
                    C[(size_t)(row_b + reg) * HID + col] =
                        __float2bfloat16(fmaxf(v, 0.f));
                }
            }
        }
    } else {
        const int head = (n0 >> 6) + wn;      // wave covers one head's 64 cols
        float bj[4], rj[4];
#pragma unroll
        for (int j = 0; j < 4; ++j) {
            bj[j] = K1b[head * 64 + j * 16 + lm];
            rj[j] = RH[head * 64 + j * 16 + lm];
        }
#pragma unroll
        for (int i = 0; i < 4; ++i) {
            int row0 = m0 + wm * 64 + i * 16 + quad * 4;
#pragma unroll
            for (int reg = 0; reg < 4; ++reg) {
                float p = 0.f;
#pragma unroll
                for (int j = 0; j < 4; ++j)
                    p = fmaf(fmaxf(acc[i][j][reg] + bj[j], 0.f), rj[j], p);
                p += __shfl_xor(p, 1, 64);
                p += __shfl_xor(p, 2, 64);
                p += __shfl_xor(p, 4, 64);
                p += __shfl_xor(p, 8, 64);
                if (lm == 0) {
                    int row = row0 + reg;
                    int b = row >> 11, l = row & (L - 1);
                    dots[((b * H + head) << 11) + l] = p;
                    if (fabsf(p - 0.5f) < MARGIN) {
                        int idx = atomicAdd(fixcnt, 1);
                        if (idx < FIXCAP) fixlist[idx] = row * 16 + head;
                    }
                }
            }
        }
    }
}

// ---------------------------------------------------------------------------
// Fix-up: one block per flagged row (grid-stride over compacted list).
// ---------------------------------------------------------------------------
__global__ __launch_bounds__(256) void fixup_kernel(
    const float* __restrict__ hs,      // (BS*L, 768) fp32
    const float* __restrict__ W,       // (768, 768) K1_w fp32
    const float* __restrict__ bias,
    const float* __restrict__ RH,
    const int* __restrict__ fixlist,
    const int* __restrict__ fixcnt,
    float* __restrict__ dots)
{
    __shared__ float hrow[HID];
    __shared__ float psum[4][64];

    const int tid = threadIdx.x;
    const int n = min(*fixcnt, FIXCAP);

    for (int item = blockIdx.x; item < n; item += FIXGRID) {
        int packed = fixlist[item];
        int row = packed >> 4, head = packed & 15;
        int b = row >> 11, l = row & (L - 1);

#pragma unroll
        for (int i = 0; i < 3; ++i)
            hrow[tid + i * 256] = hs[(size_t)row * HID + tid + i * 256];
        __syncthreads();

        const int d = tid & 63, kq = tid >> 6;
        float a0 = 0.f, a1 = 0.f;
#pragma unroll 8
        for (int i = 0; i < 96; ++i) {
            int k = kq + i * 8;
            a0 = fmaf(W[(size_t)k * HID + head * 64 + d], hrow[k], a0);
            a1 = fmaf(W[(size_t)(k + 4) * HID + head * 64 + d], hrow[k + 4], a1);
        }
        psum[kq][d] = a0 + a1;
        __syncthreads();
        if (tid < 64) {
            float v = psum[0][tid] + psum[1][tid] + psum[2][tid] +
                      psum[3][tid] + bias[head * 64 + tid];
            v = fmaxf(v, 0.f) * RH[head * 64 + tid];
#pragma unroll
            for (int s = 1; s < 64; s <<= 1) v += __shfl_xor(v, s, 64);
            if (tid == 0) dots[((size_t)(b * H + head) << 11) + l] = v;
        }
        __syncthreads();
    }
}

// ---------------------------------------------------------------------------
// Scan: rank/select tables. Pg[bh][l] = # valid in [1..l]; Sg[bh][j] = j-th
// valid index (1-based).
// ---------------------------------------------------------------------------
__global__ __launch_bounds__(256) void scan_kernel(
    const float* __restrict__ dots,   // (BS*H, L)
    unsigned short* __restrict__ Pg,  // (BS*H, L)
    unsigned short* __restrict__ Sg)  // (BS*H, L)
{
    __shared__ int wsum[4];
    const int bh = blockIdx.x;
    const int tid = threadIdx.x;
    const int base = tid * 8;
    const int lane = tid & 63, w = tid >> 6;

    int m[8], c[8];
    int run = 0;
#pragma unroll
    for (int i = 0; i < 8; ++i) {
        int l = base + i;
        m[i] = (l >= 1 && dots[((size_t)bh << 11) + l] > 0.5f) ? 1 : 0;
        run += m[i];
        c[i] = run;
    }
    int sc = run;
#pragma unroll
    for (int s = 1; s < 64; s <<= 1) {
        int v = __shfl_up(sc, s, 64);
        if (lane >= s) sc += v;
    }
    if (lane == 63) wsum[w] = sc;
    __syncthreads();
    int woff = 0;
    for (int i = 0; i < 4; ++i) if (i < w) woff += wsum[i];
    const int ex = woff + sc - run;

    union { unsigned short s[8]; uint4 q; } up;
#pragma unroll
    for (int i = 0; i < 8; ++i) {
        int pc = ex + c[i];
        up.s[i] = (unsigned short)pc;
        if (m[i]) Sg[((size_t)bh << 11) + pc] = (unsigned short)(base + i);
    }
    *(uint4*)&Pg[((size_t)bh << 11) + base] = up.q;
}

// ---------------------------------------------------------------------------
// Gather v5 (unchanged): block = (ltile of 64, bh); stage S-range rows to
// LDS, precomputed slot table, coalesced float4 stores.
// ---------------------------------------------------------------------------
__global__ __launch_bounds__(256) void gather_kernel(
    const __hip_bfloat16* __restrict__ V1,   // (8192, 768) bf16
    const unsigned short* __restrict__ Pg,
    const unsigned short* __restrict__ Sg,
    const float* __restrict__ bw,            // (H, 2R)
    float* __restrict__ out)                 // (8192, 768) fp32
{
    __shared__ __hip_bfloat16 Vs[97 * 72];   // slot pitch 144 B (16B aligned)
    __shared__ unsigned short Ptile[65];     // P[l0-1 .. l0+63]
    __shared__ short slots[64 * 32];         // [ll][r] -> staging slot (0=zero)
    __shared__ float sw[2 * R];
    __shared__ int sT;

    const int bh = blockIdx.y;
    const int b = bh / H, h = bh % H;
    const int l0 = blockIdx.x * 64;
    const int tid = threadIdx.x;

    if (tid < 65) {
        int l = l0 - 1 + tid;
        Ptile[tid] = (l >= 0) ? Pg[((size_t)bh << 11) + l] : (unsigned short)0;
    } else if (tid < 65 + 2 * R) {
        sw[tid - 65] = bw[h * (2 * R) + (tid - 65)];
    } else if (tid == 100) {
        sT = Pg[((size_t)bh << 11) + (L - 1)];
    }
    __syncthreads();

    const int T = sT;
    const int a = max(1, (int)Ptile[1] - (R - 1));
    const int bj = min(T, (int)Ptile[63] + R);
    const int nr = max(0, bj - a + 1);       // <= 95

    const __hip_bfloat16* Vbase = V1 + (size_t)b * L * HID + h * HD;
    for (int it = tid; it < (nr + 1) * 8; it += 256) {
        int slot = it >> 3, oct = it & 7;
        int row = slot ? (int)Sg[((size_t)bh << 11) + a + slot - 1] : 0;
        *(uint4*)&Vs[slot * 72 + oct * 8] =
            *(const uint4*)&Vbase[(size_t)row * HID + oct * 8];
    }
#pragma unroll
    for (int q = 0; q < 8; ++q) {
        int i = tid + q * 256;
        int ll = i >> 5, r = i & 31;
        int l = l0 + ll;
        int Pl = Ptile[1 + ll], Plm1 = Ptile[ll];
        int j, ok;
        if (r < R) { j = Pl - r;             ok = (l >= 1) && (j >= 1); }
        else       { j = Plm1 + 1 + (r - R); ok = (l >= 1) && (j <= T); }
        slots[i] = (short)(ok ? (j - a + 1) : 0);
    }
    __syncthreads();

    const int d8 = tid & 7, lg = tid >> 3;   // lg 0..31

#pragma unroll
    for (int li = 0; li < 2; ++li) {
        int ll = lg + 32 * li;               // 0..63
        int l = l0 + ll;
        float acc0 = 0.f, acc1 = 0.f, acc2 = 0.f, acc3 = 0.f;
        float acc4 = 0.f, acc5 = 0.f, acc6 = 0.f, acc7 = 0.f;
#pragma unroll
        for (int r = 0; r < 2 * R; ++r) {
            int slot = slots[ll * 32 + r];   // broadcast within d8 octet
            float wv = sw[r];
            uint4 uv = *(const uint4*)&Vs[slot * 72 + d8 * 8];
            acc0 = fmaf(wv, __uint_as_float(uv.x << 16), acc0);
            acc1 = fmaf(wv, __uint_as_float(uv.x & 0xffff0000u), acc1);
            acc2 = fmaf(wv, __uint_as_float(uv.y << 16), acc2);
            acc3 = fmaf(wv, __uint_as_float(uv.y & 0xffff0000u), acc3);
            acc4 = fmaf(wv, __uint_as_float(uv.z << 16), acc4);
            acc5 = fmaf(wv, __uint_as_float(uv.z & 0xffff0000u), acc5);
            acc6 = fmaf(wv, __uint_as_float(uv.w << 16), acc6);
            acc7 = fmaf(wv, __uint_as_float(uv.w & 0xffff0000u), acc7);
        }
        float* op = &out[((size_t)b * L + l) * HID + h * HD + d8 * 8];
        float4 o0, o1;
        o0.x = acc0; o0.y = acc1; o0.z = acc2; o0.w = acc3;
        o1.x = acc4; o1.y = acc5; o1.z = acc6; o1.w = acc7;
        *(float4*)op = o0;
        *(float4*)(op + 4) = o1;
    }
}

extern "C" void kernel_launch(void* const* d_in, const int* in_sizes, int n_in,
                              void* d_out, int out_size, void* d_ws, size_t ws_size,
                              hipStream_t stream) {
    const float* hs  = (const float*)d_in[0];
    const float* K1w = (const float*)d_in[1];
    const float* K1b = (const float*)d_in[2];
    const float* V1w = (const float*)d_in[3];
    const float* V1b = (const float*)d_in[4];
    const float* RH  = (const float*)d_in[5];
    const float* bw  = (const float*)d_in[6];
    float* out = (float*)d_out;

    // Abf lives in d_out (25 MB fp32 area; Abf needs 12.6 MB). Dead before
    // gather_kernel overwrites d_out — stream-serial, safe (validated R7/R8).
    __hip_bfloat16* Abf = (__hip_bfloat16*)d_out;

    // workspace layout (total ~15.8 MB)
    char* ws = (char*)d_ws;
    __hip_bfloat16* WtV = (__hip_bfloat16*)ws;                 // 1,179,648
    __hip_bfloat16* WtK = (__hip_bfloat16*)(ws + 1179648);     // 1,179,648
    __hip_bfloat16* V1  = (__hip_bfloat16*)(ws + 2359296);     // 12,582,912
    float* dots = (float*)(ws + 14942208);                     //   393,216
    unsigned short* Pg = (unsigned short*)(ws + 15335424);     //   196,608
    unsigned short* Sg = (unsigned short*)(ws + 15532032);     //   196,608
    int* fixlist = (int*)(ws + 15728640);                      //    65,536
    int* fixcnt  = (int*)(ws + 15794176);                      //         4

    // 1152 transpose blocks + 6144 convert blocks in one launch
    prep_kernel<<<1152 + (BS * L * HID) / (256 * 4), 256, 0, stream>>>(
        K1w, V1w, hs, WtK, WtV, Abf, fixcnt);
    gemm_fused<<<dim3(BS * L / 128, 12), 256, 0, stream>>>(
        Abf, WtK, WtV, K1b, V1b, RH, dots, fixlist, fixcnt, V1);
    fixup_kernel<<<FIXGRID, 256, 0, stream>>>(hs, K1w, K1b, RH, fixlist, fixcnt, dots);
    scan_kernel<<<BS * H, 256, 0, stream>>>(dots, Pg, Sg);
    gather_kernel<<<dim3(L / 64, BS * H), 256, 0, stream>>>(V1, Pg, Sg, bw, out);
}